// Round 7
// baseline (589.319 us; speedup 1.0000x reference)
//
#include <hip/hip_runtime.h>
#include <hip/hip_bf16.h>

typedef __attribute__((ext_vector_type(8))) short short8;
typedef __attribute__((ext_vector_type(4))) float f32x4;
typedef __attribute__((ext_vector_type(16))) float f32x16;

#define LRELU_SLOPE 0.2f
#define ACT_GAIN 1.41421356237309515f
#define WG_RGB 0.04419417382415922f   // 1/sqrt(512)
#define X1(v) ((((v) >> 2) ^ ((v) >> 3)) & 1)

__device__ __forceinline__ void glds16(const short* g, short* l) {
    __builtin_amdgcn_global_load_lds(
        (const __attribute__((address_space(1))) unsigned int*)g,
        (__attribute__((address_space(3))) unsigned int*)l, 16, 0, 0);
}

// ---------------- PRE1: fused init (blk<1088) + styles (<1120) + prepw (<1632)
__global__ __launch_bounds__(256) void k_pre1(
    __hip_bfloat16* __restrict__ Ypad, const float* __restrict__ rgb_b,
    float* __restrict__ img, const float* __restrict__ wsin,
    const float* __restrict__ caw, const float* __restrict__ cab,
    const float* __restrict__ raw_, const float* __restrict__ rab,
    float* __restrict__ sbuf, float* __restrict__ s2buf,
    const float* __restrict__ conv_w, float* __restrict__ w2sum,
    __hip_bfloat16* __restrict__ Abf) {
    __shared__ float shf[4608];
    int blk = blockIdx.x, tid = threadIdx.x;
    if (blk < 1088) {
        if (blk < 1040) {                   // Ypad border: 4160 slots, 4/block
            int gslot = blk*4 + (tid >> 6);
            int b = gslot / 260;
            int cell = gslot - b*260;
            int h, w;
            if (cell < 66)       { h = 0;          w = cell; }
            else if (cell < 132) { h = 65;         w = cell - 66; }
            else if (cell < 196) { h = cell - 131; w = 0; }
            else                 { h = cell - 195; w = 65; }
            short8 z = {};
            *(short8*)((short*)Ypad + (((b*66 + h)*66) + w)*512 + (tid & 63)*8) = z;
        } else {                            // img init
            int blk2 = blk - 1040;
            #pragma unroll
            for (int j = 0; j < 4; ++j) {
                int f4 = blk2*1024 + j*256 + tid;
                int b3 = f4 >> 10;
                int o3 = b3 % 3;
                float v = rgb_b[o3];
                f32x4 vv = {v, v, v, v};
                *(f32x4*)(img + f4*4) = vv;
            }
        }
    } else if (blk < 1120) {                // styles
        int idx = blk - 1088;
        int b = idx >> 1, which = idx & 1;
        int lane = tid & 63, wv = tid >> 6;
        const float* aw = which ? raw_ : caw;
        const float* ab = which ? rab : cab;
        float scale = which ? WG_RGB : 1.0f;
        float* op = which ? s2buf : sbuf;
        float* wsv = shf;
        wsv[tid]       = wsin[(b*2 + which)*512 + tid];
        wsv[tid + 256] = wsin[(b*2 + which)*512 + tid + 256];
        __syncthreads();
        for (int c = wv; c < 512; c += 4) {
            float p = 0.f;
            #pragma unroll
            for (int kk = 0; kk < 8; ++kk)
                p += aw[c*512 + kk*64 + lane] * wsv[kk*64 + lane];
            #pragma unroll
            for (int off = 32; off; off >>= 1) p += __shfl_down(p, off, 64);
            if (lane == 0) op[b*512 + c] = (p + ab[c]) * scale;
        }
    } else {                                // prepw
        int o = blk - 1120;
        float* wrow = shf;
        const f32x4* src = (const f32x4*)(conv_w + o*4608);
        #pragma unroll
        for (int r = 0; r < 5; ++r) {
            int idx = tid + (r << 8);
            if (idx < 1152) *(f32x4*)&wrow[idx*4] = src[idx];
        }
        __syncthreads();
        #pragma unroll
        for (int j = 0; j < 2; ++j) {
            int c = tid + (j << 8);
            float sum = 0.f;
            #pragma unroll
            for (int t = 0; t < 9; ++t) {
                float v = wrow[c*9 + t];
                sum += v*v;
                Abf[(t*512 + o)*512 + c] = __float2bfloat16(v);
            }
            w2sum[o*512 + c] = sum;
        }
    }
}

// ---------------- PRE2: fused dcoef (blk<2048) + ypad (vectorized stores)
__global__ __launch_bounds__(256) void k_pre2(
    const float* __restrict__ sbuf, const float* __restrict__ w2sum,
    const float* __restrict__ s2buf, const float* __restrict__ rgb_w,
    float* __restrict__ dcoef, float* __restrict__ rgbc,
    const float* __restrict__ cst, __hip_bfloat16* __restrict__ Ypad) {
    __shared__ float tile[64][65];
    __shared__ float sv[64];
    int blk = blockIdx.x, tid = threadIdx.x;
    if (blk < 2048) {                       // dcoef + rgbc
        int gw = blk*4 + (tid >> 6);
        int lane = tid & 63;
        int b = gw >> 9, o = gw & 511;
        float acc = 0.f;
        #pragma unroll
        for (int i = 0; i < 8; ++i) {
            int c = (i << 6) + lane;
            float svv = sbuf[(b << 9) + c];
            acc += svv*svv*w2sum[(o << 9) + c];
        }
        #pragma unroll
        for (int off = 32; off; off >>= 1) acc += __shfl_down(acc, off, 64);
        if (lane == 0) dcoef[(b << 9) + o] = rsqrtf(acc + 1e-8f);
        if (blk < 96) {
            int flat = blk*256 + tid;
            int bb = flat / 1536;
            int r  = flat - bb*1536;
            int c  = r & 511;
            rgbc[flat] = rgb_w[r] * s2buf[bb*512 + c];
        }
    } else {                                // ypad interior, short8 stores
        int blk2 = blk - 2048;
        int b = blk2 >> 6, h = blk2 & 63;
        for (int cc = 0; cc < 8; ++cc) {
            int c0 = cc << 6;
            #pragma unroll
            for (int it = 0; it < 16; ++it) {
                int cl = (it << 2) + (tid >> 6);
                int w = tid & 63;
                tile[cl][w] = cst[(c0 + cl)*4096 + (h << 6) + w];
            }
            if (tid < 64) sv[tid] = sbuf[(b << 9) + c0 + tid];
            __syncthreads();
            #pragma unroll
            for (int it = 0; it < 2; ++it) {
                int u = (it << 8) + tid;        // 0..511 = 64 w x 8 cgroups
                int w = u >> 3, cg = u & 7;
                short8 v;
                #pragma unroll
                for (int j = 0; j < 8; ++j) {
                    float f = sv[cg*8 + j] * tile[cg*8 + j][w];
                    __hip_bfloat16 bf = __float2bfloat16(f);
                    v[j] = reinterpret_cast<short&>(bf);
                }
                *(short8*)((short*)Ypad + (((b*66 + h + 1)*66) + (w + 1))*512
                           + c0 + cg*8) = v;
            }
            __syncthreads();
        }
    }
}

// ---------------- main conv GEMM: R6 structure (512 thr, 256x256, K32 phases,
// A 4-slot ring dist-3, tight per-phase vmcnt, X1 conflict-free swizzle) +
// EXPLICIT counted lgkmcnt(6) before each MFMA cluster. Theory: the 50-53%
// plateau across R2/R3/R6 is a conservative compiler lgkmcnt(0) at cluster
// heads (waits for the just-issued NEXT-phase read-ahead -> serializes LDS
// burst with MFMA every phase). lgkmcnt(6) allows exactly the 6 newest DS
// reads to stay outstanding at each cluster head (verified for both MMCLs
// and the prologue preload). sched_barrier(0) after each wait (rule 18).
__global__ __launch_bounds__(512, 2) void conv_gemm(
    const short* __restrict__ Abf,   // [9][512][512] bf16
    const short* __restrict__ Ypad,  // [16][66][66][512] bf16
    const float* __restrict__ dcoef, // [16][512]
    const float* __restrict__ noise, // [4096]
    const float* __restrict__ nstr,  // [1]
    const float* __restrict__ bias,  // [512]
    const float* __restrict__ rgbc,  // [16][3][512]
    float* __restrict__ xout,        // [16][512][4096]
    float* __restrict__ img)         // [16][3][4096], pre-init to rgb_b
{
    __shared__ short SH[59392];       // 118784B: Aring 64KB + B 52KB
    short* Aring = SH;                // [4 slot][2 ks][256 row][16c]
    short* Bbuf  = SH + 32768;        // [2 half][2 ks][416 pos][16c]
    float (*red)[3][2] = (float (*)[3][2])SH;   // post-loop overlay

    int tid = threadIdx.x, lane = tid & 63, wv = tid >> 6;   // wv 0..7
    int wr = wv >> 2, wc = wv & 3;    // wave tile rows wr*128, cols wc*64
    int ml32 = lane & 31, hi = lane >> 5;

    int blk = blockIdx.x;
    int xcd = blk & 7, idx = blk >> 3;
    int v = xcd * 64 + idx;           // bijective: 512 blocks, 64 per XCD
    int mblk = v & 1, nblk = v >> 1;  // nblk 0..255
    int b = nblk >> 4;
    int hw0 = (nblk & 15) << 8;       // 256 hw per block
    int h0 = hw0 >> 6;                // top padded row of 6-row halo window
    int o0 = mblk << 8;

    // ---- B staging sources: slot j = ks*832 + pos*2 + half (pos padded to 416)
    int bsrc[3];
    #pragma unroll
    for (int r = 0; r < 3; ++r) {
        int j = tid + (r << 9);
        int ks = (j >= 832) ? 1 : 0;
        int pe = (j - ks*832) >> 1;
        int pos = pe > 395 ? 395 : pe;     // clamp pad slots (never read)
        int half = j & 1;
        int q = half ^ X1(pos);
        int hl = pos / 66, ww = pos - hl*66;
        bsrc[r] = (((b*66 + h0 + hl)*66) + ww)*512 + ks*16 + q*8;
    }
    int bsrc3;
    {
        int j = 1536 + wv*16 + (lane & 15);   // remainder: lane<16 of each wave
        int pe = (j - 832) >> 1;
        int pos = pe > 395 ? 395 : pe;
        int half = j & 1;
        int q = half ^ X1(pos);
        int hl = pos / 66, ww = pos - hl*66;
        bsrc3 = (((b*66 + h0 + hl)*66) + ww)*512 + 16 + q*8;   // ks=1
    }
    // ---- A staging sources: round r = ks; row = tid>>1, half = tid&1
    int agofs[2];
    #pragma unroll
    for (int r = 0; r < 2; ++r) {
        int row = tid >> 1, half = tid & 1;
        int q = half ^ X1(row);
        agofs[r] = ((o0 + row) << 9) + r*16 + q*8;
    }
    // ---- frag read precompute
    int aro[4];
    #pragma unroll
    for (int mi = 0; mi < 4; ++mi) {
        int row = wr*128 + mi*32 + ml32;
        aro[mi] = row*16 + ((hi ^ X1(row)) << 3);
    }
    int pb0 = wc*66 + ml32;
    const int BPA[9] = {0, 1, 2, 66, 67, 68, 132, 133, 134};

    short* AW = Aring + wv*512;       // wave-uniform A write base

    f32x16 acc[4][2] = {};
    short8 faA[4], fbA[2], faB[4], fbB[2];

    // ---- prologue: B chunk0 -> half0 (4 issues), A slots 0..2 (6 issues)
    #pragma unroll
    for (int r = 0; r < 3; ++r)
        glds16(Ypad + bsrc[r], Bbuf + wv*512 + r*4096);
    if ((lane & 63) < 16) glds16(Ypad + bsrc3, Bbuf + 12288 + wv*128);
    #pragma unroll
    for (int t = 0; t < 3; ++t) {
        glds16(Abf + (t << 18) + agofs[0], AW + t*8192);
        glds16(Abf + (t << 18) + agofs[1], AW + t*8192 + 4096);
    }
    asm volatile("s_waitcnt vmcnt(2)" ::: "memory");   // slot2 pair may fly
    __builtin_amdgcn_s_barrier();
    // preload faA/fbA: slot0, ks0, tap0, half0 (6 DS ops, may stay in flight
    // until PH(0)'s lgkmcnt(6))
    #pragma unroll
    for (int mi = 0; mi < 4; ++mi)
        faA[mi] = *(const short8*)(Aring + aro[mi]);
    #pragma unroll
    for (int ni = 0; ni < 2; ++ni) {
        int p_ = pb0 + ni*32;
        fbA[ni] = *(const short8*)(Bbuf + p_*16 + ((hi ^ X1(p_)) << 3));
    }

    constexpr int VMP[9] = {3, 3, 3, 3, 2, 2, 2, 2, 2};

#define MMCL(FA, FB)                                                        \
    __builtin_amdgcn_s_setprio(1);                                          \
    _Pragma("unroll")                                                       \
    for (int mi = 0; mi < 4; ++mi)                                          \
        _Pragma("unroll")                                                   \
        for (int ni = 0; ni < 2; ++ni)                                      \
            acc[mi][ni] = __builtin_amdgcn_mfma_f32_32x32x16_bf16(          \
                FA[mi], FB[ni], acc[mi][ni], 0, 0, 0);                      \
    __builtin_amdgcn_s_setprio(0);

#define PH(TAP)                                                             \
    {                                                                       \
        int rr  = (rb + (TAP)) & 3;                                         \
        int rrN = (rb + (TAP) + 1) & 3;                                     \
        int rw  = (rb + (TAP) + 3) & 3;                                     \
        constexpr int TAPN = ((TAP) + 1) % 9;                               \
        constexpr int TAPP = ((TAP) < 6) ? (TAP) + 3 : (TAP) - 6;           \
        /* ks1 frags of current phase (6 DS ops) */                         \
        _Pragma("unroll")                                                   \
        for (int mi = 0; mi < 4; ++mi)                                      \
            faB[mi] = *(const short8*)(Aring + rr*8192 + 4096 + aro[mi]);   \
        _Pragma("unroll")                                                   \
        for (int ni = 0; ni < 2; ++ni) {                                    \
            int p_ = pb0 + BPA[(TAP)] + ni*32;                              \
            fbB[ni] = *(const short8*)(Bcur + 6656 + p_*16                  \
                                       + ((hi ^ X1(p_)) << 3));             \
        }                                                                   \
        /* glds prefetch: A pair for slot rw; B round for next chunk */     \
        { const short* asrc_ = Abf + (TAPP << 18) + (((TAP) < 6) ? c0 : c0n); \
          glds16(asrc_ + agofs[0], AW + rw*8192);                           \
          glds16(asrc_ + agofs[1], AW + rw*8192 + 4096); }                  \
        if ((TAP) < 3) glds16(Ypad + bsrc[(TAP)] + c0n, BWn + (TAP)*4096);  \
        if ((TAP) == 3) { if ((lane & 63) < 16)                             \
            glds16(Ypad + bsrc3 + c0n, BRm); }                              \
        __builtin_amdgcn_sched_barrier(0);                                  \
        /* allow the 6 just-issued ks1 reads to stay in flight */           \
        asm volatile("s_waitcnt lgkmcnt(6)" ::: "memory");                  \
        __builtin_amdgcn_sched_barrier(0);                                  \
        MMCL(faA, fbA)                                                      \
        __builtin_amdgcn_sched_barrier(0);                                  \
        /* next-phase ks0 frags (6 DS ops) */                               \
        { const short* BbN = ((TAP) == 8) ? Bnxt : Bcur;                    \
          _Pragma("unroll")                                                 \
          for (int mi = 0; mi < 4; ++mi)                                    \
              faA[mi] = *(const short8*)(Aring + rrN*8192 + aro[mi]);       \
          _Pragma("unroll")                                                 \
          for (int ni = 0; ni < 2; ++ni) {                                  \
              int p_ = pb0 + BPA[TAPN] + ni*32;                             \
              fbA[ni] = *(const short8*)(BbN + p_*16                        \
                                         + ((hi ^ X1(p_)) << 3));           \
          } }                                                               \
        __builtin_amdgcn_sched_barrier(0);                                  \
        /* allow the 6 read-ahead reads to stay in flight */                \
        asm volatile("s_waitcnt lgkmcnt(6)" ::: "memory");                  \
        __builtin_amdgcn_sched_barrier(0);                                  \
        MMCL(faB, fbB)                                                      \
        asm volatile("s_waitcnt vmcnt(%0)" :: "i"(VMP[(TAP)]) : "memory");  \
        __builtin_amdgcn_s_barrier();                                       \
    }

    for (int ch = 0; ch < 16; ++ch) {
        int c0 = ch << 5;
        int c0n = (c0 + 32) & 511;        // wraps on last chunk (dummy-safe)
        int rb = ch & 3;                   // (9*ch) mod 4
        int half = ch & 1;
        const short* Bcur = Bbuf + half*13312;
        const short* Bnxt = Bbuf + (half ^ 1)*13312;
        short* BWn = (short*)Bnxt + wv*512;
        short* BRm = (short*)Bnxt + 12288 + wv*128;
        PH(0) PH(1) PH(2) PH(3) PH(4) PH(5) PH(6) PH(7) PH(8)
    }
#undef PH
#undef MMCL

    // drain in-flight glds before overlaying red on Aring
    asm volatile("s_waitcnt vmcnt(0)" ::: "memory");
    __builtin_amdgcn_s_barrier();

    // ---------------- epilogue: demod + noise + bias + lrelu + store + ToRGB
    // C/D layout (32x32): col = lane&31, row = (r&3) + 8*(r>>2) + 4*hi
    float ns = nstr[0];
    float pr0[2] = {0.f, 0.f}, pr1[2] = {0.f, 0.f}, pr2[2] = {0.f, 0.f};
    #pragma unroll
    for (int mi = 0; mi < 4; ++mi) {
        int ob = o0 + wr*128 + mi*32 + hi*4;
        f32x4 dc[4], bs[4], c0r[4], c1r[4], c2r[4];
        #pragma unroll
        for (int g = 0; g < 4; ++g) {
            dc[g]  = *(const f32x4*)(dcoef + (b << 9) + ob + g*8);
            bs[g]  = *(const f32x4*)(bias + ob + g*8);
            c0r[g] = *(const f32x4*)(rgbc + b*1536 + ob + g*8);
            c1r[g] = *(const f32x4*)(rgbc + b*1536 + 512 + ob + g*8);
            c2r[g] = *(const f32x4*)(rgbc + b*1536 + 1024 + ob + g*8);
        }
        #pragma unroll
        for (int ni = 0; ni < 2; ++ni) {
            int nl = wc*64 + ni*32 + ml32;
            int hw = hw0 + nl;
            float nz = noise[hw] * ns;
            #pragma unroll
            for (int g = 0; g < 4; ++g)
                #pragma unroll
                for (int t = 0; t < 4; ++t) {
                    float vv = acc[mi][ni][g*4 + t] * dc[g][t] + nz + bs[g][t];
                    vv = (vv < 0.f ? LRELU_SLOPE*vv : vv) * ACT_GAIN;
                    xout[(((b << 9) + ob + g*8 + t) << 12) + hw] = vv;
                    pr0[ni] += vv * c0r[g][t];
                    pr1[ni] += vv * c1r[g][t];
                    pr2[ni] += vv * c2r[g][t];
                }
        }
    }
    #pragma unroll
    for (int ni = 0; ni < 2; ++ni) {
        pr0[ni] += __shfl_down(pr0[ni], 32, 64);
        pr1[ni] += __shfl_down(pr1[ni], 32, 64);
        pr2[ni] += __shfl_down(pr2[ni], 32, 64);
    }
    if (lane < 32) {
        #pragma unroll
        for (int ni = 0; ni < 2; ++ni) {
            int nl = wc*64 + ni*32 + ml32;
            red[nl][0][wr] = pr0[ni];
            red[nl][1][wr] = pr1[ni];
            red[nl][2][wr] = pr2[ni];
        }
    }
    __syncthreads();
    for (int p = tid; p < 768; p += 512) {
        int o3 = p >> 8, nl = p & 255;
        atomicAdd(img + ((b*3 + o3) << 12) + hw0 + nl, red[nl][o3][0] + red[nl][o3][1]);
    }
}

extern "C" void kernel_launch(void* const* d_in, const int* in_sizes, int n_in,
                              void* d_out, int out_size, void* d_ws, size_t ws_size,
                              hipStream_t stream) {
    (void)in_sizes; (void)n_in; (void)out_size; (void)ws_size;
    const float* wsin   = (const float*)d_in[0];   // [16][2][512]
    const float* cst    = (const float*)d_in[1];   // [512][64][64]
    const float* conv_w = (const float*)d_in[2];   // [512][512][3][3]
    const float* conv_b = (const float*)d_in[3];   // [512]
    const float* caw    = (const float*)d_in[4];   // [512][512]
    const float* cab    = (const float*)d_in[5];   // [512]
    const float* noise  = (const float*)d_in[6];   // [64][64]
    const float* nstr   = (const float*)d_in[7];   // [1]
    const float* rgb_w  = (const float*)d_in[8];   // [3][512][1][1]
    const float* rgb_b  = (const float*)d_in[9];   // [3]
    const float* raw_   = (const float*)d_in[10];  // [512][512]
    const float* rab    = (const float*)d_in[11];  // [512]

    char* wsb = (char*)d_ws;
    float* sbuf   = (float*)(wsb + 0);         // 16*512 f32
    float* s2buf  = (float*)(wsb + 32768);     // 16*512 f32
    float* dcoef  = (float*)(wsb + 65536);     // 16*512 f32
    float* rgbc   = (float*)(wsb + 98304);     // 16*3*512 f32
    float* w2sum  = (float*)(wsb + 196608);    // 512*512 f32 ([o][c])
    __hip_bfloat16* Abf  = (__hip_bfloat16*)(wsb + 1245184);  // 9*512*512 bf16
    __hip_bfloat16* Ypad = (__hip_bfloat16*)(wsb + 5963776);  // 16*66*66*512 bf16

    float* xout = (float*)d_out;               // [16][512][4096]
    float* img  = xout + 33554432;             // [16][3][4096]

    k_pre1<<<1632, 256, 0, stream>>>(Ypad, rgb_b, img, wsin, caw, cab, raw_, rab,
                                     sbuf, s2buf, conv_w, w2sum, Abf);
    k_pre2<<<3072, 256, 0, stream>>>(sbuf, w2sum, s2buf, rgb_w, dcoef, rgbc,
                                     cst, Ypad);
    conv_gemm<<<512, 512, 0, stream>>>((const short*)Abf, (const short*)Ypad,
                                       dcoef, noise, nstr, conv_b, rgbc, xout, img);
}